// Round 9
// baseline (588.833 us; speedup 1.0000x reference)
//
#include <hip/hip_runtime.h>
#include <hip/hip_bf16.h>
#include <math.h>

// ---------------------------------------------------------------------------
// MoE block: y = sum_topk2 w_e * FFN_e(x)  +  FFN_shared(x)
// T=4096, D=1024, H=4096, E=8, K=2.  bf16 MFMA compute.
// R9: deep-pipeline GEMM: BM=256/BN=128/BK=32, 3 LDS buffers (72 KB ->
// 2 blocks/CU, 4 waves/SIMD), stage(t+2) + counted vmcnt(6) -> ~48 KB
// continuously in flight per block (fixes the MLP-bound feed rate that
// capped R5-R8 at ~8-14 B/cy/CU). 2 barriers/K-tile, setprio MFMA.
// ---------------------------------------------------------------------------

typedef unsigned short ushort_t;
typedef __attribute__((ext_vector_type(8))) __bf16 bf16x8;
typedef __attribute__((ext_vector_type(4))) float f32x4;

#define T_TOK 4096
#define DDIM  1024
#define HDIM  4096
#define NEXP  8
#define SLOT_PAD 10240           // 8192 + 8*256 pad headroom (256-aligned regions)
#define M_ALL (SLOT_PAD + T_TOK) // 14336 rows: experts then shared

// workspace layout (bytes)
#define OFF_CNT   0u             // int[8] cnt + int[8] cur
#define OFF_OFFS  64u            // int[16]
#define OFF_TIDX  256u           // int[8192]
#define OFF_TW    33024u         // float[8192]
#define OFF_SLOT  65792u         // int[8192]
#define OFF_TOK   98560u         // int[10240]
#define OFF_XALL  1048576u                        // bf16 [14336][1024] = 29,360,128
#define OFF_OUTS  OFF_XALL                        // bf16 [10240][1024] (aliases Xall)
#define OFF_WT    (OFF_XALL + 29360128u)          // bf16 [9][N][K] = 75,497,472
#define OFF_H     (OFF_WT + 75497472u)            // bf16 [14336][4096] = 117,440,512

__device__ __forceinline__ ushort_t f2b(float f) {
    __hip_bfloat16 h = __float2bfloat16(f);
    return *reinterpret_cast<ushort_t*>(&h);
}
__device__ __forceinline__ float b2f(ushort_t u) {
    __hip_bfloat16 h;
    *reinterpret_cast<ushort_t*>(&h) = u;
    return __bfloat162float(h);
}
// tanh-form GELU (max |dev| from exact erf-GELU ~3e-3; bf16-safe here)
__device__ __forceinline__ float gelu_fast(float v) {
    float u = 0.7978845608f * v * (1.0f + 0.044715f * v * v);
    float t = 1.0f - 2.0f / (__expf(2.0f * u) + 1.0f);
    return 0.5f * v * (1.0f + t);
}

// -------------------------------- init -------------------------------------
__global__ void init_kernel(int* __restrict__ cnt, int* __restrict__ tok_of) {
    int i = blockIdx.x * 256 + threadIdx.x;
    if (i < 16) cnt[i] = 0;
    if (i < SLOT_PAD) tok_of[i] = -1;
}

// -------------------------------- gate -------------------------------------
__global__ void gate_kernel(const float* __restrict__ x, const float* __restrict__ gw,
                            int* __restrict__ tidx, float* __restrict__ tw,
                            int* __restrict__ cnt) {
    int t = blockIdx.x;
    int l = threadIdx.x;
    float acc[NEXP];
#pragma unroll
    for (int e = 0; e < NEXP; ++e) acc[e] = 0.f;
    for (int i = 0; i < DDIM / 64; ++i) {
        float xi = x[(size_t)t * DDIM + i * 64 + l];
#pragma unroll
        for (int e = 0; e < NEXP; ++e)
            acc[e] += xi * gw[e * DDIM + i * 64 + l];
    }
#pragma unroll
    for (int e = 0; e < NEXP; ++e)
        for (int off = 32; off; off >>= 1) acc[e] += __shfl_xor(acc[e], off);
    if (l == 0) {
        float m = acc[0];
#pragma unroll
        for (int e = 1; e < NEXP; ++e) m = fmaxf(m, acc[e]);
        float ex[NEXP], Z = 0.f;
#pragma unroll
        for (int e = 0; e < NEXP; ++e) { ex[e] = __expf(acc[e] - m); Z += ex[e]; }
        int b0 = 0;
#pragma unroll
        for (int e = 1; e < NEXP; ++e) if (ex[e] > ex[b0]) b0 = e;
        int b1 = (b0 == 0) ? 1 : 0;
#pragma unroll
        for (int e = 0; e < NEXP; ++e) if (e != b0 && ex[e] > ex[b1]) b1 = e;
        float inv = 1.0f / Z;
        tidx[2 * t] = b0; tidx[2 * t + 1] = b1;
        tw[2 * t] = ex[b0] * inv; tw[2 * t + 1] = ex[b1] * inv;
        atomicAdd(&cnt[b0], 1);
        atomicAdd(&cnt[b1], 1);
    }
}

// ------------------------------ offsets ------------------------------------
__global__ void offs_kernel(const int* __restrict__ cnt, int* __restrict__ offs) {
    if (threadIdx.x == 0 && blockIdx.x == 0) {
        int o = 0;
#pragma unroll
        for (int e = 0; e < NEXP; ++e) {
            offs[e] = o;
            o += (cnt[e] + 255) & ~255;
        }
        offs[NEXP] = o;
    }
}

// ------------------------------- assign ------------------------------------
// slot order within an expert is atomic-race-dependent, but the OUTPUT is
// permutation-invariant (each slot row computed independently).
__global__ void assign_kernel(const int* __restrict__ tidx, const int* __restrict__ offs,
                              int* __restrict__ cur, int* __restrict__ slot_of,
                              int* __restrict__ tok_of) {
    int i = blockIdx.x * 256 + threadIdx.x;
    if (i >= 2 * T_TOK) return;
    int e = tidx[i];
    int s = offs[e] + atomicAdd(&cur[e], 1);
    slot_of[i] = s;
    tok_of[s] = i >> 1;
}

// ------------------------------- build X -----------------------------------
__global__ void build_x(const float* __restrict__ x, const int* __restrict__ tok_of,
                        const int* __restrict__ offs, ushort_t* __restrict__ Xall) {
    int b = blockIdx.x;
    int k = threadIdx.x * 4;
    int t;
    if (b < SLOT_PAD) {
        if (b >= offs[NEXP]) return;
        t = tok_of[b];
    } else {
        t = b - SLOT_PAD;
    }
    float4 v = make_float4(0.f, 0.f, 0.f, 0.f);
    if (t >= 0) v = *(const float4*)(x + (size_t)t * DDIM + k);
    ushort_t* p = Xall + (size_t)b * DDIM + k;
    p[0] = f2b(v.x); p[1] = f2b(v.y); p[2] = f2b(v.z); p[3] = f2b(v.w);
}

// --------------------------- transpose + cvt -------------------------------
// in [K][N] fp32 -> out [N][K] bf16 ; grid (K/64, N/64, batch)
__global__ void transpose_cvt(const float* __restrict__ in, ushort_t* __restrict__ out,
                              int K, int N) {
    __shared__ float t[64][65];
    size_t zoff = (size_t)blockIdx.z * K * N;
    in += zoff; out += zoff;
    int k0 = blockIdx.x * 64, n0 = blockIdx.y * 64;
    int c = threadIdx.x & 63, r4 = threadIdx.x >> 6;
#pragma unroll
    for (int i = 0; i < 16; ++i) {
        int r = r4 + i * 4;
        t[r][c] = in[(size_t)(k0 + r) * N + n0 + c];
    }
    __syncthreads();
#pragma unroll
    for (int i = 0; i < 16; ++i) {
        int r = r4 + i * 4;
        out[(size_t)(n0 + r) * K + k0 + c] = f2b(t[c][r]);
    }
}

// ------------------------- GEMM 256x128, BK=32, 3-buf ----------------------
// C[M,N] = act(A[M,K] @ Bt[e][N,K]^T + bias), rows grouped by expert
// (256-aligned), expert 8 = shared. 512 thr / 8 waves (2M x 4N), wave-tile
// 128x32, acc[8][2]. LDS: 3 bufs x (A 16KB + B 8KB) = 72 KB -> 2 blocks/CU
// (16 waves/CU, 4/SIMD). Pipeline: stage(t+2) -> vmcnt(6) [tile t drained;
// t+1,t+2 = 48 KB in flight, waited loads 2 iterations old] -> s_barrier ->
// ds_read+MFMA (setprio) -> s_barrier. Ring bufs (t,t+1,t+2 distinct mod 3)
// make stage/read overlap race-free. 4-chunk XOR swizzle c=q^((r>>1)&3)
// (2 lanes/granule, conflict-free) with pre-swizzled global source.
template <bool ACT_GELU, bool FFN2>
__global__ __launch_bounds__(512, 4) void gemm_moe(
    const ushort_t* __restrict__ A, const ushort_t* __restrict__ WtBase,
    const float* __restrict__ bExp, const float* __restrict__ bSh,
    ushort_t* __restrict__ Cb, float* __restrict__ Cf,
    const int* __restrict__ offs, int N, int K) {
    // ---- per-XCD patch swizzle (bijective; NM%4==0, NN%2==0) ----
    int NMt = gridDim.x, NNt = gridDim.y;
    int flat = blockIdx.y * NMt + blockIdx.x;
    int xcd = flat & 7, rank = flat >> 3;
    int PM = NMt >> 2;                    // patch rows (14)
    int PN = NNt >> 1;                    // patch cols (16 or 4)
    int pm = xcd >> 1, pn = xcd & 1;      // 4 x 2 patch grid
    int mi = pm * PM + rank / PN;
    int ni = pn * PN + rank % PN;
    int m0 = mi * 256, n0 = ni * 128;

    int e;
    if (m0 >= SLOT_PAD) {
        e = NEXP;                        // shared region
    } else {
        if (m0 >= offs[NEXP]) return;    // dead pad zone (before any barrier)
        e = 0;
        while (offs[e + 1] <= m0) e++;
    }
    const ushort_t* Bt = WtBase + (size_t)e * N * K;
    const float* bias = (e == NEXP) ? bSh : bExp + (size_t)e * N;

    __shared__ ushort_t As[3][256 * 32];   // 3 x 16 KB
    __shared__ ushort_t Bs[3][128 * 32];   // 3 x  8 KB

    int tid = threadIdx.x;
    int lane = tid & 63, wid = tid >> 6;   // 8 waves
    int wm = wid >> 2, wn = wid & 3;       // 2 x 4 wave grid
    int q = lane >> 4, lr = lane & 15;

    // staging: A has 1024 16B-chunks (2/thread), B has 512 (1/thread).
    // LDS chunk (r, c) <- global chunk u = c ^ ((r>>1)&3)  (pre-swizzled src)
    size_t AoffG[2], BoffG;
    int AoffL[2], BoffL;
#pragma unroll
    for (int it = 0; it < 2; ++it) {
        int L = it * 512 + tid;
        int r = L >> 2;
        int u = (L & 3) ^ ((r >> 1) & 3);
        AoffG[it] = (size_t)(m0 + r) * K + u * 8;
        AoffL[it] = L * 8;
    }
    {
        int L = tid;
        int r = L >> 2;
        int u = (L & 3) ^ ((r >> 1) & 3);
        BoffG = (size_t)(n0 + r) * K + u * 8;
        BoffL = L * 8;
    }

    f32x4 acc[8][2];
#pragma unroll
    for (int i = 0; i < 8; ++i)
#pragma unroll
        for (int j = 0; j < 2; ++j) acc[i][j] = (f32x4)(0.f);

    auto stage = [&](int kb, int b) {       // 3 loads per thread
        __builtin_amdgcn_global_load_lds(
            (const __attribute__((address_space(1))) void*)(A + AoffG[0] + kb),
            (__attribute__((address_space(3))) void*)(&As[b][AoffL[0]]), 16, 0, 0);
        __builtin_amdgcn_global_load_lds(
            (const __attribute__((address_space(1))) void*)(A + AoffG[1] + kb),
            (__attribute__((address_space(3))) void*)(&As[b][AoffL[1]]), 16, 0, 0);
        __builtin_amdgcn_global_load_lds(
            (const __attribute__((address_space(1))) void*)(Bt + BoffG + kb),
            (__attribute__((address_space(3))) void*)(&Bs[b][BoffL]), 16, 0, 0);
    };
    auto compute = [&](int b) {
        const ushort_t* Ab = &As[b][0];
        const ushort_t* Bb = &Bs[b][0];
        bf16x8 bfr[2];
#pragma unroll
        for (int j = 0; j < 2; ++j) {
            int r = wn * 32 + j * 16 + lr;
            int c = q ^ ((r >> 1) & 3);
            bfr[j] = *(const bf16x8*)(Bb + r * 32 + c * 8);
        }
        bf16x8 af[4];
#pragma unroll
        for (int i = 0; i < 4; ++i) {
            int r = wm * 128 + i * 16 + lr;
            int c = q ^ ((r >> 1) & 3);
            af[i] = *(const bf16x8*)(Ab + r * 32 + c * 8);
        }
        __builtin_amdgcn_s_setprio(1);
#pragma unroll
        for (int i = 0; i < 4; ++i)
#pragma unroll
            for (int j = 0; j < 2; ++j)
                acc[i][j] = __builtin_amdgcn_mfma_f32_16x16x32_bf16(
                    af[i], bfr[j], acc[i][j], 0, 0, 0);
#pragma unroll
        for (int i = 0; i < 4; ++i) {
            int r = wm * 128 + (i + 4) * 16 + lr;
            int c = q ^ ((r >> 1) & 3);
            af[i] = *(const bf16x8*)(Ab + r * 32 + c * 8);
        }
#pragma unroll
        for (int i = 0; i < 4; ++i)
#pragma unroll
            for (int j = 0; j < 2; ++j)
                acc[i + 4][j] = __builtin_amdgcn_mfma_f32_16x16x32_bf16(
                    af[i], bfr[j], acc[i + 4][j], 0, 0, 0);
        __builtin_amdgcn_s_setprio(0);
    };

    const int nk = K >> 5;                 // 32 or 128 (>= 3)
    stage(0, 0);                           // 3 outstanding
    stage(1 << 5, 1);                      // 6 outstanding
    int bc = 0, bs = 2;                    // compute buf, stage buf
    for (int t = 0; t < nk; ++t) {
        int kn = t + 2;
        if (kn >= nk) kn -= nk;            // wrap tail: vmcnt stays uniform
        stage(kn << 5, bs);                // 9 outstanding
        asm volatile("s_waitcnt vmcnt(6)" ::: "memory");  // tile t landed
        __builtin_amdgcn_s_barrier();      // all waves' tile-t loads visible
        compute(bc);
        __builtin_amdgcn_s_barrier();      // block done reading buf bc
        bc = (bc == 2) ? 0 : bc + 1;
        bs = (bs == 2) ? 0 : bs + 1;
    }

    // epilogue: C/D map col=lane&15, row=(lane>>4)*4+reg
    int colb = n0 + wn * 32 + lr;
    int rowb = m0 + wm * 128 + q * 4;
#pragma unroll
    for (int j = 0; j < 2; ++j) {
        int col = colb + j * 16;
        float bz = bias[col];
#pragma unroll
        for (int i = 0; i < 8; ++i) {
            int row = rowb + i * 16;
#pragma unroll
            for (int r = 0; r < 4; ++r) {
                float v = acc[i][j][r] + bz;
                if (ACT_GELU) v = gelu_fast(v);
                if (!FFN2 || e < NEXP)
                    Cb[(size_t)(row + r) * N + col] = f2b(v);
                else
                    Cf[(size_t)(row + r - SLOT_PAD) * N + col] = v;
            }
        }
    }
}

// ------------------------------- combine -----------------------------------
__global__ void combine_kernel(float* __restrict__ out, const ushort_t* __restrict__ OutS,
                               const int* __restrict__ slot_of, const float* __restrict__ tw) {
    int t = blockIdx.x;
    int d = threadIdx.x * 4;
    int s0 = slot_of[2 * t], s1 = slot_of[2 * t + 1];
    float w0 = tw[2 * t], w1 = tw[2 * t + 1];
    float* po = out + (size_t)t * DDIM + d;
    float4 o = *(float4*)po;
    const ushort_t* p0 = OutS + (size_t)s0 * DDIM + d;
    const ushort_t* p1 = OutS + (size_t)s1 * DDIM + d;
    o.x += w0 * b2f(p0[0]) + w1 * b2f(p1[0]);
    o.y += w0 * b2f(p0[1]) + w1 * b2f(p1[1]);
    o.z += w0 * b2f(p0[2]) + w1 * b2f(p1[2]);
    o.w += w0 * b2f(p0[3]) + w1 * b2f(p1[3]);
    *(float4*)po = o;
}

// ------------------------------- launch ------------------------------------
extern "C" void kernel_launch(void* const* d_in, const int* in_sizes, int n_in,
                              void* d_out, int out_size, void* d_ws, size_t ws_size,
                              hipStream_t stream) {
    const float* x      = (const float*)d_in[0];
    const float* gw     = (const float*)d_in[1];
    const float* w_in   = (const float*)d_in[2];
    const float* b_in   = (const float*)d_in[3];
    const float* w_out  = (const float*)d_in[4];
    const float* b_out  = (const float*)d_in[5];
    const float* sw_in  = (const float*)d_in[6];
    const float* sb_in  = (const float*)d_in[7];
    const float* sw_out = (const float*)d_in[8];
    const float* sb_out = (const float*)d_in[9];
    float* out = (float*)d_out;

    char* ws = (char*)d_ws;
    int*      cnt     = (int*)(ws + OFF_CNT);      // [0..7]=cnt, [8..15]=cur
    int*      offs    = (int*)(ws + OFF_OFFS);
    int*      tidx    = (int*)(ws + OFF_TIDX);
    float*    tw      = (float*)(ws + OFF_TW);
    int*      slot_of = (int*)(ws + OFF_SLOT);
    int*      tok_of  = (int*)(ws + OFF_TOK);
    ushort_t* Xall    = (ushort_t*)(ws + OFF_XALL);
    ushort_t* OutS    = (ushort_t*)(ws + OFF_OUTS); // aliases Xall (used after GEMM1)
    ushort_t* Wt      = (ushort_t*)(ws + OFF_WT);   // [9][N][K], FFN1 then FFN2
    ushort_t* Hbuf    = (ushort_t*)(ws + OFF_H);    // bf16 [14336][4096]

    // routing
    init_kernel<<<(SLOT_PAD + 255) / 256, 256, 0, stream>>>(cnt, tok_of);
    gate_kernel<<<T_TOK, 64, 0, stream>>>(x, gw, tidx, tw, cnt);
    offs_kernel<<<1, 64, 0, stream>>>(cnt, offs);
    assign_kernel<<<(2 * T_TOK + 255) / 256, 256, 0, stream>>>(tidx, offs, cnt + 8,
                                                               slot_of, tok_of);
    build_x<<<M_ALL, 256, 0, stream>>>(x, tok_of, offs, Xall);

    // FFN1 weights: [9][4096][1024] bf16  (w_in experts + sw_in as expert 8)
    transpose_cvt<<<dim3(DDIM / 64, HDIM / 64, NEXP), 256, 0, stream>>>(w_in, Wt, DDIM, HDIM);
    transpose_cvt<<<dim3(DDIM / 64, HDIM / 64, 1), 256, 0, stream>>>(
        sw_in, Wt + (size_t)NEXP * HDIM * DDIM, DDIM, HDIM);
    // H = gelu(Xall @ W1 + b1)
    gemm_moe<true, false><<<dim3(M_ALL / 256, HDIM / 128), 512, 0, stream>>>(
        Xall, Wt, b_in, sb_in, Hbuf, nullptr, offs, HDIM, DDIM);

    // FFN2 weights: [9][1024][4096] bf16
    transpose_cvt<<<dim3(HDIM / 64, DDIM / 64, NEXP), 256, 0, stream>>>(w_out, Wt, HDIM, DDIM);
    transpose_cvt<<<dim3(HDIM / 64, DDIM / 64, 1), 256, 0, stream>>>(
        sw_out, Wt + (size_t)NEXP * HDIM * DDIM, HDIM, DDIM);
    // expert rows -> OutS (bf16); shared rows -> out (fp32, includes bias)
    gemm_moe<false, true><<<dim3(M_ALL / 256, DDIM / 128), 512, 0, stream>>>(
        Hbuf, Wt, b_out, sb_out, OutS, out, offs, DDIM, HDIM);

    // out += w0*OutS[slot0] + w1*OutS[slot1]
    combine_kernel<<<T_TOK, 256, 0, stream>>>(out, OutS, slot_of, tw);
    (void)in_sizes; (void)n_in; (void)out_size; (void)ws_size;
}